// Round 7
// baseline (2102.433 us; speedup 1.0000x reference)
//
#include <hip/hip_runtime.h>
#include <math.h>

#define TT 2048
#define UU 64
#define BB 256
#define NTHR 128        // 2 waves: wave0 = layer-0 producer (ALL gates), wave1 = consumer
#define CH 16           // timesteps per chunk (one barrier per chunk)
#define NCH (TT / CH)   // 128 chunks -> 129 barriers total (vs 2050 in r0-r6)
#define NSLOT 32        // h ring slots (2 chunks deep, double-buffered)
#define KREG 20         // h-inputs 0..19: weights in VGPRs (80) ; 20..63: LDS table
#define KLDS (UU - KREG)

typedef float v2f __attribute__((ext_vector_type(2)));
typedef float v4f __attribute__((ext_vector_type(4)));

// Fast activations on v_exp_f32 / v_rcp_f32 (~1e-7 abs err; threshold 3.45e-6;
// validated at absmax 9.5e-7 in rounds 0-6).
__device__ __forceinline__ float frcp(float x) { return __builtin_amdgcn_rcpf(x); }
__device__ __forceinline__ float fsigmoid(float x) { return frcp(1.0f + __expf(-x)); }
__device__ __forceinline__ float ftanh(float x) { return 1.0f - 2.0f * frcp(1.0f + __expf(2.0f * x)); }

// Packed dual-FMA: a.{x,y} += h.{x,y} * w.{x,y}  (one VOP3P instruction).
__device__ __forceinline__ void pkfma(v2f& a, v2f h, v2f w) {
    asm("v_pk_fma_f32 %0, %1, %2, %0" : "+v"(a) : "v"(h), "v"(w));
}

// ROUNDS 0-6 POST-MORTEM: all seven structures land 1089-1296us because they
// share a serial skeleton -- one multi-wave __syncthreads PER STEP + a z LDS
// round-trip + an h LDS round-trip. r6 proved weight residency is NOT the
// lever (reg-half fit the 132 grant, still slower). This round deletes the
// skeleton:
//   * ONE producer wave computes all 4 gates: lane u owns unit u, so
//     z_i,z_j,z_f,z_o never leave the lane -> NO z exchange, NO per-step
//     barrier. Only 129 barriers total (chunk protocol with the consumer).
//   * Weights: 20 h-rows in named v4f regs (80 VGPR; requirement ~120 <
//     the 132 the RA measurably grants) + 44 h-rows streamed per step from
//     a 44KB LDS table via constant-offset ds_read_b128 (addresses are
//     t-invariant: zero addressing VALU; an opaque per-iteration pin stops
//     LICM from hoisting them into registers).
//   * h broadcast: (h,h) splat ring, 32 uniform ds_read_b128 -> 128
//     v_pk_fma_f32 in 8 chains x 16. Chain order, k-order and activation
//     order are BIT-IDENTICAL to r4 (same zij/zfo reduction tree).
// Wave 1 (consumer): r0's proven chunk protocol -- after barrier k2+1 it
// processes steps [k2*16, k2*16+15] from the 32-slot ring (producer
// overwrites a slot only after barrier k2+2 -> structurally race-free),
// layer-1 LSTM + dense, banks output per-lane, coalesced flush every 64.
__global__
__attribute__((amdgpu_flat_work_group_size(NTHR, NTHR)))
__attribute__((amdgpu_waves_per_eu(1, 1)))
void lstm_ts_kernel(
    const float* __restrict__ x, const float* __restrict__ W0,
    const float* __restrict__ b0, const float* __restrict__ W1,
    const float* __restrict__ b1, const float* __restrict__ Wd,
    const float* __restrict__ bd, float* __restrict__ out)
{
    __shared__ __align__(16) float xbuf[TT];          // 8 KB
    __shared__ __align__(16) v4f  WT[KLDS][UU];       // 44 KB: k=20..63, (i,j,f,o)
    __shared__ __align__(16) float ring[NSLOT][2*UU]; // 16 KB: (h,h) splat pairs
    __shared__ float red[2];

    const int tid = threadIdx.x;
    const int wid = tid >> 6;
    const int u = tid & 63;
    const int b = blockIdx.x;
    const float* xrow = x + b * TT;
    float* outrow = out + b * TT;

    // ---- prologue: stage x (+sumsq) and the LDS weight table ----
    float ss = 0.f;
    for (int i = tid; i < TT; i += NTHR) {
        float v = xrow[i];
        xbuf[i] = v;
        ss += v * v;
    }
    // WT[k-KREG][uu] = (Wi[k][uu], Wj[k][uu], Wf[k][uu], Wo[k][uu])
    for (int idx = tid; idx < KLDS * UU; idx += NTHR) {
        const int k = KREG + (idx >> 6), uu = idx & 63;
        const float* r_ = W0 + (1 + k) * 256;
        v4f e;
        e.x = r_[uu]; e.y = r_[64 + uu]; e.z = r_[128 + uu]; e.w = r_[192 + uu];
        WT[k - KREG][uu] = e;
    }
    #pragma unroll
    for (int m = 1; m < 64; m <<= 1) ss += __shfl_xor(ss, m, 64);
    if (u == 0) red[wid] = ss;
    if (wid == 0) {  // h_{-1} = 0: step 0 reads slot (0-1)&31 = 31
        ring[NSLOT - 1][2 * u] = 0.f;
        ring[NSLOT - 1][2 * u + 1] = 0.f;
    }
    __syncthreads();  // B0

    if (wid == 0) {
        // ========== PRODUCER: layer-0 LSTM, one wave, all 4 gates ==========
        const float sq = red[0] + red[1];
        const float scale = 1.0f / sqrtf(fmaxf(sq, 1e-12f));  // precise, once

        // 20 named v4f = 80 weight VGPRs (requirement ~120 < 132 grant).
        // R{k} = (Wi[k][u], Wj[k][u], Wf[k][u], Wo[k][u]).
        #define DECLR(k) v4f R##k; { const float* r_ = W0 + (1 + (k)) * 256; \
            R##k.x = r_[u]; R##k.y = r_[64 + u]; \
            R##k.z = r_[128 + u]; R##k.w = r_[192 + u]; } \
            asm volatile("" : "+v"(R##k));
        DECLR(0)  DECLR(1)  DECLR(2)  DECLR(3)  DECLR(4)
        DECLR(5)  DECLR(6)  DECLR(7)  DECLR(8)  DECLR(9)
        DECLR(10) DECLR(11) DECLR(12) DECLR(13) DECLR(14)
        DECLR(15) DECLR(16) DECLR(17) DECLR(18) DECLR(19)
        #undef DECLR

        const float wxi = W0[u] * scale,       wxj = W0[64 + u] * scale;
        const float wxf = W0[128 + u] * scale, wxo = W0[192 + u] * scale;
        const float bci = b0[u],       bcj = b0[64 + u];
        const float bcf = b0[128 + u], bco = b0[192 + u];

        float c0 = 0.f;

        for (int t = 0; t < TT; ++t) {
            // opaque per-iteration base: LICM cannot hoist the 44 WT reads
            // into registers (which would re-trigger the r1/r2 spill storm)
            int uoff = u;
            asm volatile("" : "+v"(uoff));
            const v4f* wtp = &WT[0][0] + uoff;

            const float xr = xbuf[t];                     // uniform broadcast
            const float* hs = ring[(t + NSLOT - 1) & (NSLOT - 1)];  // h_{t-1}

            // 8 chains (4 ij + 4 fo), 16 deep; x-term folded into chain 0.
            // Chain assignment and k-order bit-identical to r4.
            v2f ai0, ai1 = 0.f, ai2 = 0.f, ai3 = 0.f;
            v2f af0, af1 = 0.f, af2 = 0.f, af3 = 0.f;
            ai0.x = fmaf(xr, wxi, bci); ai0.y = fmaf(xr, wxj, bcj);
            af0.x = fmaf(xr, wxf, bcf); af0.y = fmaf(xr, wxo, bco);

            // m-th MAC: splat pair (h2m,h2m,h2m+1,h2m+1) x rows k=2m,2m+1
            #define MACX(m, Wa, Wb, AiE, AiO, AfE, AfO) { \
                v4f hv_ = *(const v4f*)(hs + 4 * (m)); \
                v2f hlo_ = __builtin_shufflevector(hv_, hv_, 0, 1); \
                v2f hhi_ = __builtin_shufflevector(hv_, hv_, 2, 3); \
                pkfma(AiE, hlo_, __builtin_shufflevector(Wa, Wa, 0, 1)); \
                pkfma(AfE, hlo_, __builtin_shufflevector(Wa, Wa, 2, 3)); \
                pkfma(AiO, hhi_, __builtin_shufflevector(Wb, Wb, 0, 1)); \
                pkfma(AfO, hhi_, __builtin_shufflevector(Wb, Wb, 2, 3)); }
            #define MACLDS(m, AiE, AiO, AfE, AfO) { \
                v4f Wa_ = wtp[(2 * (m)     - KREG) * UU]; \
                v4f Wb_ = wtp[(2 * (m) + 1 - KREG) * UU]; \
                MACX(m, Wa_, Wb_, AiE, AiO, AfE, AfO) }

            MACX(0,  R0,  R1,  ai0, ai1, af0, af1)
            MACX(1,  R2,  R3,  ai2, ai3, af2, af3)
            MACX(2,  R4,  R5,  ai0, ai1, af0, af1)
            MACX(3,  R6,  R7,  ai2, ai3, af2, af3)
            MACX(4,  R8,  R9,  ai0, ai1, af0, af1)
            MACX(5,  R10, R11, ai2, ai3, af2, af3)
            MACX(6,  R12, R13, ai0, ai1, af0, af1)
            MACX(7,  R14, R15, ai2, ai3, af2, af3)
            MACX(8,  R16, R17, ai0, ai1, af0, af1)
            MACX(9,  R18, R19, ai2, ai3, af2, af3)
            MACLDS(10, ai0, ai1, af0, af1) MACLDS(11, ai2, ai3, af2, af3)
            MACLDS(12, ai0, ai1, af0, af1) MACLDS(13, ai2, ai3, af2, af3)
            MACLDS(14, ai0, ai1, af0, af1) MACLDS(15, ai2, ai3, af2, af3)
            MACLDS(16, ai0, ai1, af0, af1) MACLDS(17, ai2, ai3, af2, af3)
            MACLDS(18, ai0, ai1, af0, af1) MACLDS(19, ai2, ai3, af2, af3)
            MACLDS(20, ai0, ai1, af0, af1) MACLDS(21, ai2, ai3, af2, af3)
            MACLDS(22, ai0, ai1, af0, af1) MACLDS(23, ai2, ai3, af2, af3)
            MACLDS(24, ai0, ai1, af0, af1) MACLDS(25, ai2, ai3, af2, af3)
            MACLDS(26, ai0, ai1, af0, af1) MACLDS(27, ai2, ai3, af2, af3)
            MACLDS(28, ai0, ai1, af0, af1) MACLDS(29, ai2, ai3, af2, af3)
            MACLDS(30, ai0, ai1, af0, af1) MACLDS(31, ai2, ai3, af2, af3)
            #undef MACLDS
            #undef MACX

            const v2f zij = (ai0 + ai1) + (ai2 + ai3);
            const v2f zfo = (af0 + af1) + (af2 + af3);

            // ---- unit update: z never left the lane ----
            c0 = fsigmoid(zfo.x + 1.0f) * c0 + fsigmoid(zij.x) * ftanh(zij.y);
            const float h = fsigmoid(zfo.y) * ftanh(c0);

            // publish (h,h) splat: next step's broadcast AND the consumer
            v2f hh; hh.x = h; hh.y = h;
            *(v2f*)(&ring[t & (NSLOT - 1)][2 * u]) = hh;

            if ((t & (CH - 1)) == (CH - 1)) __syncthreads();  // 1 per 16 steps
        }
    } else {
        // ================= CONSUMER: layer 1 + dense + store =================
        const float w1v0 = W1[u * 4 + 0], w1v1 = W1[u * 4 + 1];
        const float w1v2 = W1[u * 4 + 2], w1v3 = W1[u * 4 + 3];
        const float w1h0 = W1[256], w1h1 = W1[257], w1h2 = W1[258], w1h3 = W1[259];
        const float b10 = b1[0], b11 = b1[1], b12 = b1[2], b13 = b1[3];
        const float wd = Wd[0], bdv = bd[0];

        float c1 = 0.f, h1 = 0.f, oval = 0.f;

        for (int k2 = 0; k2 < NCH; ++k2) {
            __syncthreads();  // chunk k2 is now fully in the ring
            const int sbase = k2 * CH;
            for (int si = 0; si < CH; ++si) {
                const int s = sbase + si;
                const float hu = ring[s & (NSLOT - 1)][2 * u];  // 8B stride: free
                float p0 = hu * w1v0, p1 = hu * w1v1, p2 = hu * w1v2, p3 = hu * w1v3;
                #pragma unroll
                for (int m = 1; m < 64; m <<= 1) {
                    p0 += __shfl_xor(p0, m, 64);
                    p1 += __shfl_xor(p1, m, 64);
                    p2 += __shfl_xor(p2, m, 64);
                    p3 += __shfl_xor(p3, m, 64);
                }
                const float z1i = p0 + fmaf(h1, w1h0, b10);
                const float z1j = p1 + fmaf(h1, w1h1, b11);
                const float z1f = p2 + fmaf(h1, w1h2, b12);
                const float z1o = p3 + fmaf(h1, w1h3, b13);
                c1 = fsigmoid(z1f + 1.0f) * c1 + fsigmoid(z1i) * ftanh(z1j);
                h1 = fsigmoid(z1o) * ftanh(c1);
                const float ov = fmaf(h1, wd, bdv);
                if ((s & 63) == u) oval = ov;
                if ((s & 63) == 63) outrow[(s & ~63) + u] = oval;
            }
        }
    }
}

extern "C" void kernel_launch(void* const* d_in, const int* in_sizes, int n_in,
                              void* d_out, int out_size, void* d_ws, size_t ws_size,
                              hipStream_t stream) {
    const float* x  = (const float*)d_in[0];
    const float* W0 = (const float*)d_in[1];
    const float* b0 = (const float*)d_in[2];
    const float* W1 = (const float*)d_in[3];
    const float* b1 = (const float*)d_in[4];
    const float* Wd = (const float*)d_in[5];
    const float* bd = (const float*)d_in[6];
    float* out = (float*)d_out;
    lstm_ts_kernel<<<BB, NTHR, 0, stream>>>(x, W0, b0, W1, b1, Wd, bd, out);
}

// Round 8
// 1845.232 us; speedup vs baseline: 1.1394x; 1.1394x over previous
//
#include <hip/hip_runtime.h>
#include <math.h>

#define TT 2048
#define UU 64
#define BB 256
#define NTHR 256   // 4 waves; ALL are layer-0 producers; layer-1 inlined redundantly

typedef float v2f __attribute__((ext_vector_type(2)));
typedef float v4f __attribute__((ext_vector_type(4)));

// Fast activations on v_exp_f32 / v_rcp_f32 (~1e-7 abs err; threshold 3.45e-6;
// validated at absmax 9.5e-7 in rounds 0-7).
__device__ __forceinline__ float frcp(float x) { return __builtin_amdgcn_rcpf(x); }
__device__ __forceinline__ float fsigmoid(float x) { return frcp(1.0f + __expf(-x)); }
__device__ __forceinline__ float ftanh(float x) { return 1.0f - 2.0f * frcp(1.0f + __expf(2.0f * x)); }

// Packed dual-FMA: a.{x,y} += h.{x,y} * w.{x,y}  (one VOP3P instruction).
__device__ __forceinline__ void pkfma(v2f& a, v2f h, v2f w) {
    asm("v_pk_fma_f32 %0, %1, %2, %0" : "+v"(a) : "v"(h), "v"(w));
}

// v[idx] for idx = 0..3 with idx bits (b0g,b1g): 3 cndmasks.
__device__ __forceinline__ float sel4(float v0, float v1, float v2, float v3,
                                      int b0g, int b1g) {
    const float lo = b0g ? v1 : v0;
    const float hi = b0g ? v3 : v2;
    return b1g ? hi : lo;
}

// ROUND-7 POST-MORTEM: no-barrier single-producer = 2460cy/step (issue-bound).
// r0-r6 ledger: r4's 1276cy/step was most likely bound by the CONSUMER wave --
// its 6-level shfl_xor reduce (6 serial ds_bpermute latencies) + L1 act sat
// inside the per-step barrier. THIS ROUND: no consumer wave at all.
//
// 4 waves, all producers. Wave w owns units 16w..16w+15; lane l computes gate
// (l>>4) of unit (l&15)+16w -> 64 weights/lane (32 named v2f over k-pairs).
//   * matvec: 16 uniform ds_read_b128 of h[4m..4m+3] + 32 v_pk_fma_f32
//     (4 chains x 8), horizontal add -> z for THIS lane's (gate,unit).
//   * z exchange: in-wave 3-op shfl_xor butterfly (16,32,32) + sel4 maps
//     v[k^g] -> (zi,zj,zf,zo). No LDS round-trip, no barrier.
//   * act: redundant in the 4 gate-lanes of each unit (bit-identical).
//   * h publish: lanes l<16 write h to ring[t&1][unit] (64 floats total).
//   * layer-1: per-lane products h.W1row, 4-level row-16 shuffle reduce
//     (independent of the z chain -> overlaps matvec), lane15 writes a v4f
//     partial to pbuf[t&3][w]. After the ONE barrier per step, EVERY wave
//     sums the 4 partials + runs the scalar L1 LSTM redundantly (ILP overlaps
//     it with the next step's matvec). Wave 0 banks/stores the output.
// pbuf is 4-slot: reader of slot (t-1)&3 (window B_t..B_t+1) vs next writer
// slot (t+1)&3 -- distinct mod 4, race-free. ring is 2-slot (>=1 barrier sep).
// Barriers: 1 + TT + 1, uniform across all waves.
__global__
__attribute__((amdgpu_flat_work_group_size(NTHR, NTHR)))
__attribute__((amdgpu_waves_per_eu(1, 1)))
void lstm_ts_kernel(
    const float* __restrict__ x, const float* __restrict__ W0,
    const float* __restrict__ b0, const float* __restrict__ W1,
    const float* __restrict__ b1, const float* __restrict__ Wd,
    const float* __restrict__ bd, float* __restrict__ out)
{
    __shared__ __align__(16) float xbuf[TT];       // 8 KB
    __shared__ __align__(16) float ring[2][UU];    // h ring, 512 B
    __shared__ __align__(16) v4f  pbuf[4][4];      // L1 partials [slot][wave]
    __shared__ float red[4];

    const int tid = threadIdx.x;
    const int wid = tid >> 6;       // wave 0..3
    const int l   = tid & 63;
    const int g   = l >> 4;         // gate 0..3 (i,j,f,o)
    const int q   = l & 15;
    const int unit = 16 * wid + q;  // this lane's unit
    const int col  = g * 64 + unit; // this lane's W0 column
    const int b = blockIdx.x;
    const float* xrow = x + b * TT;
    float* outrow = out + b * TT;

    // ---- prologue: stage x, sum of squares over T (all 4 waves) ----
    float ss = 0.f;
    for (int i = tid; i < TT; i += NTHR) {
        float v = xrow[i];
        xbuf[i] = v;
        ss += v * v;
    }
    #pragma unroll
    for (int m = 1; m < 64; m <<= 1) ss += __shfl_xor(ss, m, 64);
    if (l == 0) red[wid] = ss;
    if (tid < UU) ring[1][tid] = 0.f;   // h_{-1} = 0 (iter 0 reads ring[1])
    __syncthreads();  // B0

    const float sq = (red[0] + red[1]) + (red[2] + red[3]);
    const float scale = 1.0f / sqrtf(fmaxf(sq, 1e-12f));  // precise, once

    // 32 named v2f = 64 weight VGPRs: WPm = (W[2m][col], W[2m+1][col]).
    #define DECLW(m) v2f WP##m; { const float* r_ = W0 + (1 + 2*(m)) * 256 + col; \
        WP##m.x = r_[0]; WP##m.y = r_[256]; } \
        asm volatile("" : "+v"(WP##m));
    DECLW(0)  DECLW(1)  DECLW(2)  DECLW(3)  DECLW(4)  DECLW(5)  DECLW(6)  DECLW(7)
    DECLW(8)  DECLW(9)  DECLW(10) DECLW(11) DECLW(12) DECLW(13) DECLW(14) DECLW(15)
    DECLW(16) DECLW(17) DECLW(18) DECLW(19) DECLW(20) DECLW(21) DECLW(22) DECLW(23)
    DECLW(24) DECLW(25) DECLW(26) DECLW(27) DECLW(28) DECLW(29) DECLW(30) DECLW(31)
    #undef DECLW

    const float wx = W0[col] * scale;   // l2-norm scale folded into x-weight
    const float bc = b0[col];

    // layer-1 constants (uniform scalar loads; every wave keeps its own copy)
    const v4f w1r = *(const v4f*)&W1[unit * 4];   // W1 row of THIS lane's unit
    const float w1h0 = W1[256], w1h1 = W1[257], w1h2 = W1[258], w1h3 = W1[259];
    const float b10 = b1[0], b11 = b1[1], b12 = b1[2], b13 = b1[3];
    const float wd = Wd[0], bdv = bd[0];

    const int b0g = g & 1, b1g = g & 2;

    float c0 = 0.f, h_own = 0.f;          // layer-0 state (this lane's unit)
    float c1 = 0.f, h1 = 0.f, oval = 0.f; // layer-1 state (redundant per wave)

    // L1 step s: partials(h_s) written in iter s+1 to pbuf[(s+1)&3], LSTM'd
    // in iter s+2 (after B) from pbuf[(t-1)&3]. Output banked by lane s&63.
    #define L1STEP(s, PB) { \
        const v4f zp = ((PB)[0] + (PB)[1]) + ((PB)[2] + (PB)[3]); \
        const float z1i = zp.x + fmaf(h1, w1h0, b10); \
        const float z1j = zp.y + fmaf(h1, w1h1, b11); \
        const float z1f = zp.z + fmaf(h1, w1h2, b12); \
        const float z1o = zp.w + fmaf(h1, w1h3, b13); \
        c1 = fsigmoid(z1f + 1.0f) * c1 + fsigmoid(z1i) * ftanh(z1j); \
        h1 = fsigmoid(z1o) * ftanh(c1); \
        const float ov = fmaf(h1, wd, bdv); \
        if (((s) & 63) == l) oval = ov; \
        if (wid == 0 && ((s) & 63) == 63) outrow[((s) & ~63) + l] = oval; \
    }

    for (int t = 0; t < TT; ++t) {
        const float xr = xbuf[t];              // uniform broadcast
        const float* hs = ring[(t + 1) & 1];   // h_{t-1}

        // ---- matvec: 16 uniform b128 reads + 32 pkfma (4 chains x 8) ----
        v2f a0, a1 = 0.f, a2 = 0.f, a3 = 0.f;
        a0.x = fmaf(xr, wx, bc); a0.y = 0.f;

        #define MACP(m, WA, WB, A, B) { \
            v4f hv_ = *(const v4f*)(hs + 4 * (m)); \
            v2f hA_ = __builtin_shufflevector(hv_, hv_, 0, 1); \
            v2f hB_ = __builtin_shufflevector(hv_, hv_, 2, 3); \
            pkfma(A, hA_, WA); pkfma(B, hB_, WB); \
        }
        MACP(0,  WP0,  WP1,  a0, a1) MACP(1,  WP2,  WP3,  a2, a3)
        MACP(2,  WP4,  WP5,  a0, a1) MACP(3,  WP6,  WP7,  a2, a3)
        MACP(4,  WP8,  WP9,  a0, a1) MACP(5,  WP10, WP11, a2, a3)
        MACP(6,  WP12, WP13, a0, a1) MACP(7,  WP14, WP15, a2, a3)
        MACP(8,  WP16, WP17, a0, a1) MACP(9,  WP18, WP19, a2, a3)
        MACP(10, WP20, WP21, a0, a1) MACP(11, WP22, WP23, a2, a3)
        MACP(12, WP24, WP25, a0, a1) MACP(13, WP26, WP27, a2, a3)
        MACP(14, WP28, WP29, a0, a1) MACP(15, WP30, WP31, a2, a3)
        #undef MACP

        const v2f sz = (a0 + a1) + (a2 + a3);
        const float zown = sz.x + sz.y;        // z for (gate g, unit)

        // ---- in-wave z butterfly: v[m] = z of gate g^m for this unit ----
        const float v0 = zown;
        const float v1 = __shfl_xor(zown, 16, 64);
        const float v2 = __shfl_xor(zown, 32, 64);
        const float v3 = __shfl_xor(v1,   32, 64);
        const float zi = sel4(v0, v1, v2, v3, b0g, b1g);
        const float zj = sel4(v1, v0, v3, v2, b0g, b1g);
        const float zf = sel4(v2, v3, v0, v1, b0g, b1g);
        const float zo = sel4(v3, v2, v1, v0, b0g, b1g);

        // ---- L1 partials of h_{t-1} (independent; overlaps the above) ----
        {
            float px = h_own * w1r.x, py = h_own * w1r.y;
            float pz = h_own * w1r.z, pw = h_own * w1r.w;
            #pragma unroll
            for (int m = 1; m < 16; m <<= 1) {
                px += __shfl_xor(px, m, 64);
                py += __shfl_xor(py, m, 64);
                pz += __shfl_xor(pz, m, 64);
                pw += __shfl_xor(pw, m, 64);
            }
            if (l == 15) {
                v4f pp; pp.x = px; pp.y = py; pp.z = pz; pp.w = pw;
                pbuf[t & 3][wid] = pp;
            }
        }

        // ---- unit update (redundant across the 4 gate-lanes of the unit) ----
        c0 = fsigmoid(zf + 1.0f) * c0 + fsigmoid(zi) * ftanh(zj);
        h_own = fsigmoid(zo) * ftanh(c0);
        if (l < 16) ring[t & 1][unit] = h_own;   // g==0 lanes publish h_t

        __syncthreads();  // B_t (the ONLY barrier per step)

        // ---- layer-1 LSTM for step t-2 (every wave, redundant; ILP
        //      overlaps it with the next iteration's matvec) ----
        if (t >= 2) L1STEP(t - 2, pbuf[(t - 1) & 3])
    }

    // ---- epilogue: L1 steps TT-2 and TT-1 ----
    L1STEP(TT - 2, pbuf[(TT - 1) & 3])
    {
        float px = h_own * w1r.x, py = h_own * w1r.y;
        float pz = h_own * w1r.z, pw = h_own * w1r.w;
        #pragma unroll
        for (int m = 1; m < 16; m <<= 1) {
            px += __shfl_xor(px, m, 64);
            py += __shfl_xor(py, m, 64);
            pz += __shfl_xor(pz, m, 64);
            pw += __shfl_xor(pw, m, 64);
        }
        if (l == 15) {
            v4f pp; pp.x = px; pp.y = py; pp.z = pz; pp.w = pw;
            pbuf[TT & 3][wid] = pp;
        }
    }
    __syncthreads();
    L1STEP(TT - 1, pbuf[TT & 3])
    #undef L1STEP
}

extern "C" void kernel_launch(void* const* d_in, const int* in_sizes, int n_in,
                              void* d_out, int out_size, void* d_ws, size_t ws_size,
                              hipStream_t stream) {
    const float* x  = (const float*)d_in[0];
    const float* W0 = (const float*)d_in[1];
    const float* b0 = (const float*)d_in[2];
    const float* W1 = (const float*)d_in[3];
    const float* b1 = (const float*)d_in[4];
    const float* Wd = (const float*)d_in[5];
    const float* bd = (const float*)d_in[6];
    float* out = (float*)d_out;
    lstm_ts_kernel<<<BB, NTHR, 0, stream>>>(x, W0, b0, W1, b1, Wd, bd, out);
}

// Round 9
// 1677.128 us; speedup vs baseline: 1.2536x; 1.1002x over previous
//
#include <hip/hip_runtime.h>
#include <math.h>

#define TT 2048
#define UU 64
#define BB 256
#define NTHR 192   // 3 waves: wave0/1 = producers (split by UNIT), wave2 = consumer

typedef float v2f __attribute__((ext_vector_type(2)));
typedef float v4f __attribute__((ext_vector_type(4)));

// Fast activations on v_exp_f32 / v_rcp_f32 (~1e-7 abs err; threshold 3.45e-6;
// validated at absmax 9.5e-7 in rounds 0-8).
__device__ __forceinline__ float frcp(float x) { return __builtin_amdgcn_rcpf(x); }
__device__ __forceinline__ float fsigmoid(float x) { return frcp(1.0f + __expf(-x)); }
__device__ __forceinline__ float ftanh(float x) { return 1.0f - 2.0f * frcp(1.0f + __expf(2.0f * x)); }

// Packed dual-FMA: a.{x,y} += h.{x,y} * w.{x,y}  (one VOP3P instruction).
__device__ __forceinline__ void pkfma(v2f& a, v2f h, v2f w) {
    asm("v_pk_fma_f32 %0, %1, %2, %0" : "+v"(a) : "v"(h), "v"(w));
}

// ROUND-8 POST-MORTEM: shuffle-everything (19 ds_bpermute/step) + redundant
// L1 on all waves = bpermute-latency bound (1845us). r4 (1089us) remains the
// best skeleton. THIS ROUND = r4 with its two remaining serial cuts:
//  (1) z-exchange INTRA-wave: producers split by UNIT not by gate-pair.
//      Wave w owns units 32w..32w+31; lane l: p=l>>5 picks gate-pair
//      ((i,j) for p=0, (f,o) for p=1), q=l&31 picks unit 32w+q. The z
//      exchange is ONE shfl_xor(32) pair (~40cy) instead of the LDS
//      write->barrier->read round-trip (~180cy+tail).
//  (2) barrier moves AFTER the h-ring write: the post-barrier tail
//      (z-read + act, ~300cy in r4) vanishes -- the next matvec starts
//      directly from the shared splat ring.
// Per-lane weights/matvec/act are BIT-IDENTICAL to r4 (64 named v2f, same
// MAC2 chains, same k-order, same activation order) -> same absmax.
//
// Ring protocol (2-slot, shared): step t writes ring[t&1] pre-barrier
// (window (B(t),B(t+1))); producers read slot (t+1)&1 in (B(t),B(t+1)) --
// written before B(t), rewritten after B(t+1): race-free. Consumer reads
// ring[t&1] for step t in (B(t+1),B(t+2)); rewritten after B(t+2): race-free
// (zero lag). All 3 waves execute exactly 1 + TT barriers.
__global__
__attribute__((amdgpu_flat_work_group_size(NTHR, NTHR)))
__attribute__((amdgpu_waves_per_eu(1, 1)))
void lstm_ts_kernel(
    const float* __restrict__ x, const float* __restrict__ W0,
    const float* __restrict__ b0, const float* __restrict__ W1,
    const float* __restrict__ b1, const float* __restrict__ Wd,
    const float* __restrict__ bd, float* __restrict__ out)
{
    __shared__ __align__(16) float xbuf[TT];        // 8 KB
    __shared__ __align__(16) float ring[2][2 * UU]; // shared (h,h) splat ring, 1 KB
    __shared__ float red[3];

    const int tid = threadIdx.x;
    const int wid = tid >> 6;
    const int l = tid & 63;
    const int b = blockIdx.x;
    const float* xrow = x + b * TT;
    float* outrow = out + b * TT;

    // ---- prologue: stage x, sum of squares over T (all 3 waves) ----
    float ss = 0.f;
    for (int i = tid; i < TT; i += NTHR) {
        float v = xrow[i];
        xbuf[i] = v;
        ss += v * v;
    }
    #pragma unroll
    for (int m = 1; m < 64; m <<= 1) ss += __shfl_xor(ss, m, 64);
    if (l == 0) red[wid] = ss;
    if (tid < 2 * UU) ring[1][tid] = 0.f;  // h_{-1} = 0 (step 0 reads ring[1])
    __syncthreads();  // B0

    if (wid < 2) {
        // ===== PRODUCER wave 'wid': units 32w..32w+31, gate-pair by lane half =====
        const int p = l >> 5;            // 0 -> gates (i,j), 1 -> gates (f,o)
        const int q = l & 31;
        const int unit = 32 * wid + q;   // this lane's unit
        const int go = p * 128;          // gate-pair column offset
        const float sq = (red[0] + red[1]) + red[2];
        const float scale = 1.0f / sqrtf(fmaxf(sq, 1e-12f));  // precise, once

        // 64 named v2f = 128 weight VGPRs (identical footprint to r4).
        // WPk = (W[k][go+unit], W[k][go+64+unit]).
        #define DECLW(k) v2f WP##k; { const float* r_ = W0 + (1 + (k)) * 256 + go; \
            WP##k.x = r_[unit]; WP##k.y = r_[64 + unit]; } \
            asm volatile("" : "+v"(WP##k));
        DECLW(0)  DECLW(1)  DECLW(2)  DECLW(3)  DECLW(4)  DECLW(5)  DECLW(6)  DECLW(7)
        DECLW(8)  DECLW(9)  DECLW(10) DECLW(11) DECLW(12) DECLW(13) DECLW(14) DECLW(15)
        DECLW(16) DECLW(17) DECLW(18) DECLW(19) DECLW(20) DECLW(21) DECLW(22) DECLW(23)
        DECLW(24) DECLW(25) DECLW(26) DECLW(27) DECLW(28) DECLW(29) DECLW(30) DECLW(31)
        DECLW(32) DECLW(33) DECLW(34) DECLW(35) DECLW(36) DECLW(37) DECLW(38) DECLW(39)
        DECLW(40) DECLW(41) DECLW(42) DECLW(43) DECLW(44) DECLW(45) DECLW(46) DECLW(47)
        DECLW(48) DECLW(49) DECLW(50) DECLW(51) DECLW(52) DECLW(53) DECLW(54) DECLW(55)
        DECLW(56) DECLW(57) DECLW(58) DECLW(59) DECLW(60) DECLW(61) DECLW(62) DECLW(63)
        #undef DECLW

        const float wxa = W0[go + unit] * scale;       // x-weight, gate a (i or f)
        const float wxb = W0[go + 64 + unit] * scale;  // gate b (j or o)
        const float bca = b0[go + unit], bcb = b0[go + 64 + unit];

        float c0 = 0.f;

        for (int t = 0; t < TT; ++t) {
            const float xr = xbuf[t];               // uniform broadcast
            const float* hs = ring[(t + 1) & 1];    // h_{t-1} splats (shared)

            // 4 chains x 16 deep; x-term folded into chain 0 (r4 bit-identical)
            v2f a0, a1 = 0.f, a2 = 0.f, a3 = 0.f;
            a0.x = fmaf(xr, wxa, bca); a0.y = fmaf(xr, wxb, bcb);

            // one uniform b128 read = (h2k,h2k,h2k+1,h2k+1) -> 2 pk_fma
            #define MAC2(k2, Wa, Wb, Ae, Ao) { \
                v4f hv_ = *(const v4f*)(hs + 4 * (k2)); \
                v2f hlo_ = __builtin_shufflevector(hv_, hv_, 0, 1); \
                v2f hhi_ = __builtin_shufflevector(hv_, hv_, 2, 3); \
                pkfma(Ae, hlo_, Wa); pkfma(Ao, hhi_, Wb); \
            }
            MAC2(0,  WP0,  WP1,  a0, a1) MAC2(1,  WP2,  WP3,  a2, a3)
            MAC2(2,  WP4,  WP5,  a0, a1) MAC2(3,  WP6,  WP7,  a2, a3)
            MAC2(4,  WP8,  WP9,  a0, a1) MAC2(5,  WP10, WP11, a2, a3)
            MAC2(6,  WP12, WP13, a0, a1) MAC2(7,  WP14, WP15, a2, a3)
            MAC2(8,  WP16, WP17, a0, a1) MAC2(9,  WP18, WP19, a2, a3)
            MAC2(10, WP20, WP21, a0, a1) MAC2(11, WP22, WP23, a2, a3)
            MAC2(12, WP24, WP25, a0, a1) MAC2(13, WP26, WP27, a2, a3)
            MAC2(14, WP28, WP29, a0, a1) MAC2(15, WP30, WP31, a2, a3)
            MAC2(16, WP32, WP33, a0, a1) MAC2(17, WP34, WP35, a2, a3)
            MAC2(18, WP36, WP37, a0, a1) MAC2(19, WP38, WP39, a2, a3)
            MAC2(20, WP40, WP41, a0, a1) MAC2(21, WP42, WP43, a2, a3)
            MAC2(22, WP44, WP45, a0, a1) MAC2(23, WP46, WP47, a2, a3)
            MAC2(24, WP48, WP49, a0, a1) MAC2(25, WP50, WP51, a2, a3)
            MAC2(26, WP52, WP53, a0, a1) MAC2(27, WP54, WP55, a2, a3)
            MAC2(28, WP56, WP57, a0, a1) MAC2(29, WP58, WP59, a2, a3)
            MAC2(30, WP60, WP61, a0, a1) MAC2(31, WP62, WP63, a2, a3)
            #undef MAC2

            const v2f zown = (a0 + a1) + (a2 + a3);  // own gate-pair (zA, zB)

            // ---- z exchange: ONE intra-wave hop (lane l <-> l^32) ----
            const float ox = __shfl_xor(zown.x, 32, 64);
            const float oy = __shfl_xor(zown.y, 32, 64);
            const float zi = p ? ox : zown.x;
            const float zj = p ? oy : zown.y;
            const float zf = p ? zown.x : ox;
            const float zo = p ? zown.y : oy;

            // ---- unit update (redundant in lane pair l, l^32) ----
            c0 = fsigmoid(zf + 1.0f) * c0 + fsigmoid(zi) * ftanh(zj);
            const float h = fsigmoid(zo) * ftanh(c0);

            // publish (h,h) splat to the SHARED ring (p==0 lanes; 8B stride)
            if (p == 0) {
                v2f hh; hh.x = h; hh.y = h;
                *(v2f*)(&ring[t & 1][2 * unit]) = hh;
            }
            __syncthreads();  // B(t+1): h_t visible to all waves
        }
    } else {
        // ================= CONSUMER: layer 1 + dense + store =================
        const float w1v0 = W1[l * 4 + 0], w1v1 = W1[l * 4 + 1];
        const float w1v2 = W1[l * 4 + 2], w1v3 = W1[l * 4 + 3];
        const float w1h0 = W1[256], w1h1 = W1[257], w1h2 = W1[258], w1h3 = W1[259];
        const float b10 = b1[0], b11 = b1[1], b12 = b1[2], b13 = b1[3];
        const float wd = Wd[0], bdv = bd[0];

        float c1 = 0.f, h1 = 0.f, oval = 0.f;

        // zero-lag: after B(t+1), ring[t&1] holds h_t; it is rewritten only
        // after B(t+2) -> the read window (B(t+1),B(t+2)) is race-free.
        for (int t = 0; t < TT; ++t) {
            __syncthreads();  // B(t+1)
            const float hu = ring[t & 1][2 * l];  // 8B stride: 2-way, free
            float p0 = hu * w1v0, p1 = hu * w1v1, p2 = hu * w1v2, p3 = hu * w1v3;
            #pragma unroll
            for (int m = 1; m < 64; m <<= 1) {
                p0 += __shfl_xor(p0, m, 64);
                p1 += __shfl_xor(p1, m, 64);
                p2 += __shfl_xor(p2, m, 64);
                p3 += __shfl_xor(p3, m, 64);
            }
            const float z1i = p0 + fmaf(h1, w1h0, b10);
            const float z1j = p1 + fmaf(h1, w1h1, b11);
            const float z1f = p2 + fmaf(h1, w1h2, b12);
            const float z1o = p3 + fmaf(h1, w1h3, b13);
            c1 = fsigmoid(z1f + 1.0f) * c1 + fsigmoid(z1i) * ftanh(z1j);
            h1 = fsigmoid(z1o) * ftanh(c1);
            const float ov = fmaf(h1, wd, bdv);
            if ((t & 63) == l) oval = ov;
            if ((t & 63) == 63) outrow[(t & ~63) + l] = oval;
        }
    }
}

extern "C" void kernel_launch(void* const* d_in, const int* in_sizes, int n_in,
                              void* d_out, int out_size, void* d_ws, size_t ws_size,
                              hipStream_t stream) {
    const float* x  = (const float*)d_in[0];
    const float* W0 = (const float*)d_in[1];
    const float* b0 = (const float*)d_in[2];
    const float* W1 = (const float*)d_in[3];
    const float* b1 = (const float*)d_in[4];
    const float* Wd = (const float*)d_in[5];
    const float* bd = (const float*)d_in[6];
    float* out = (float*)d_out;
    lstm_ts_kernel<<<BB, NTHR, 0, stream>>>(x, W0, b0, W1, b1, Wd, bd, out);
}

// Round 10
// 999.101 us; speedup vs baseline: 2.1043x; 1.6786x over previous
//
#include <hip/hip_runtime.h>
#include <math.h>

#define TT 2048
#define UU 64
#define BB 256
#define NTHR 192   // 3 waves: wave0 = gates(i,j), wave1 = gates(f,o), wave2 = consumer

typedef float v2f __attribute__((ext_vector_type(2)));
typedef float v4f __attribute__((ext_vector_type(4)));

// Fast activations on v_exp_f32 / v_rcp_f32 (~1e-7 abs err; threshold 3.45e-6;
// validated at absmax 9.5e-7 in rounds 0-9).
__device__ __forceinline__ float frcp(float x) { return __builtin_amdgcn_rcpf(x); }
__device__ __forceinline__ float fsigmoid(float x) { return frcp(1.0f + __expf(-x)); }
__device__ __forceinline__ float ftanh(float x) { return 1.0f - 2.0f * frcp(1.0f + __expf(2.0f * x)); }

// VOP3P op_sel splat-FMA: both halves of the result consume the SAME 32-bit
// half of h -- the (h,h) splat never needs to be materialized (neither in
// LDS nor via v_mov). ll: both use h.lo; hh: both use h.hi.
__device__ __forceinline__ void pkfma_ll(v2f& a, v2f h, v2f w) {
    asm("v_pk_fma_f32 %0, %1, %2, %0 op_sel:[0,0,0] op_sel_hi:[0,1,1]"
        : "+v"(a) : "v"(h), "v"(w));
}
__device__ __forceinline__ void pkfma_hh(v2f& a, v2f h, v2f w) {
    asm("v_pk_fma_f32 %0, %1, %2, %0 op_sel:[1,0,0] op_sel_hi:[1,1,1]"
        : "+v"(a) : "v"(h), "v"(w));
}

// ROUND-9 POST-MORTEM (units fixed: FETCH_SIZE is KB -> ~1.3MB/dispatch, no
// memory problem). VALU cycles/step are ~315 in every structure; the rest is
// stall. r4 (1089us) is the proven local optimum; all six skeleton mutations
// regressed. THIS ROUND = r4 byte-for-byte except two LDS-pipe cuts:
//  (1) plain h[64] ring + op_sel splat inside pkfma: 16 uniform ds_read_b128
//      per step instead of 32, ring write b32 instead of b64. Bit-identical
//      products and accumulation order.
//  (2) own z-pair stays in registers; after the barrier only the OTHER
//      wave's pair is read (one dependent post-barrier LDS read removed).
//
// Wave 0: lane u owns (i,j) columns {u, 64+u} of W0. Wave 1: (f,o) columns.
// Per step: matvec (16 uniform b128 h reads + 64 op_sel pkfma in 4 chains),
// write own (zA,zB) pair, ONE barrier, read other pair, redundant (c0,h)
// update -- bit-identical in both waves -- write own private plain-h ring.
// Wave 2 (consumer): after barrier t processes step t-1 from wave0's ring
// (written in (B(t),B(t+1)), rewritten after B(t+2): race-free): 4-value
// 64-lane shuffle reduce + layer-1 LSTM + dense, banks output, coalesced
// flush every 64 steps. All 3 waves execute exactly 1 + TT + 1 barriers.
__global__
__attribute__((amdgpu_flat_work_group_size(NTHR, NTHR)))
__attribute__((amdgpu_waves_per_eu(1, 1)))
void lstm_ts_kernel(
    const float* __restrict__ x, const float* __restrict__ W0,
    const float* __restrict__ b0, const float* __restrict__ W1,
    const float* __restrict__ b1, const float* __restrict__ Wd,
    const float* __restrict__ bd, float* __restrict__ out)
{
    __shared__ __align__(16) float xbuf[TT];        // 8 KB
    __shared__ __align__(16) float ringS0[2][UU];   // wave0 plain-h ring
    __shared__ __align__(16) float ringS1[2][UU];   // wave1 private copy
    __shared__ __align__(16) v2f zb0[UU];           // (z_i, z_j) per unit
    __shared__ __align__(16) v2f zb1[UU];           // (z_f, z_o) per unit
    __shared__ float red[3];

    const int tid = threadIdx.x;
    const int wid = tid >> 6;
    const int u = tid & 63;
    const int b = blockIdx.x;
    const float* xrow = x + b * TT;
    float* outrow = out + b * TT;

    // ---- prologue: stage x, sum of squares over T (all 3 waves) ----
    float ss = 0.f;
    for (int i = tid; i < TT; i += NTHR) {
        float v = xrow[i];
        xbuf[i] = v;
        ss += v * v;
    }
    #pragma unroll
    for (int m = 1; m < 64; m <<= 1) ss += __shfl_xor(ss, m, 64);
    if (u == 0) red[wid] = ss;
    if (wid < 2) {  // h_{-1} = 0: step 0 reads slot 1
        (wid == 0 ? ringS0 : ringS1)[1][u] = 0.f;
    }
    __syncthreads();  // B0

    if (wid < 2) {
        // ============ PRODUCER wave 'wid': gate pair (i,j) or (f,o) ============
        const int go = wid * 128;  // column offset: 0 -> (i,j), 128 -> (f,o)
        const float sq = (red[0] + red[1]) + red[2];
        const float scale = 1.0f / sqrtf(fmaxf(sq, 1e-12f));  // precise, once

        // 64 named v2f = 128 weight VGPRs (identical to r4).
        // WPk = (W[k][go+u], W[k][go+64+u]).
        #define DECLW(k) v2f WP##k; { const float* r_ = W0 + (1 + (k)) * 256 + go; \
            WP##k.x = r_[u]; WP##k.y = r_[64 + u]; } \
            asm volatile("" : "+v"(WP##k));
        DECLW(0)  DECLW(1)  DECLW(2)  DECLW(3)  DECLW(4)  DECLW(5)  DECLW(6)  DECLW(7)
        DECLW(8)  DECLW(9)  DECLW(10) DECLW(11) DECLW(12) DECLW(13) DECLW(14) DECLW(15)
        DECLW(16) DECLW(17) DECLW(18) DECLW(19) DECLW(20) DECLW(21) DECLW(22) DECLW(23)
        DECLW(24) DECLW(25) DECLW(26) DECLW(27) DECLW(28) DECLW(29) DECLW(30) DECLW(31)
        DECLW(32) DECLW(33) DECLW(34) DECLW(35) DECLW(36) DECLW(37) DECLW(38) DECLW(39)
        DECLW(40) DECLW(41) DECLW(42) DECLW(43) DECLW(44) DECLW(45) DECLW(46) DECLW(47)
        DECLW(48) DECLW(49) DECLW(50) DECLW(51) DECLW(52) DECLW(53) DECLW(54) DECLW(55)
        DECLW(56) DECLW(57) DECLW(58) DECLW(59) DECLW(60) DECLW(61) DECLW(62) DECLW(63)
        #undef DECLW

        const float wxa = W0[go + u] * scale;       // x-weight, gate a (i or f)
        const float wxb = W0[go + 64 + u] * scale;  // gate b (j or o)
        const float bca = b0[go + u], bcb = b0[go + 64 + u];

        float (*myring)[UU] = (wid == 0) ? ringS0 : ringS1;
        v2f* zbme = (wid == 0) ? zb0 : zb1;
        v2f* zbot = (wid == 0) ? zb1 : zb0;

        float c0 = 0.f;

        for (int t = 0; t < TT; ++t) {
            const float xr = xbuf[t];               // uniform broadcast
            const float* hs = myring[(t + 1) & 1];  // h_{t-1} (own private copy)

            // 4 chains x 16 deep; x-term folded into chain 0 (r4 bit-identical:
            // a0/a1 take rows 4m,4m+1; a2/a3 take rows 4m+2,4m+3; same order).
            v2f a0, a1 = 0.f, a2 = 0.f, a3 = 0.f;
            a0.x = fmaf(xr, wxa, bca); a0.y = fmaf(xr, wxb, bcb);

            // ONE uniform b128 read = h_{4m..4m+3} -> 4 op_sel pkfma
            #define MAC4(m, Wa, Wb, Wc, Wd_) { \
                v4f hv_ = *(const v4f*)(hs + 4 * (m)); \
                v2f h01_ = __builtin_shufflevector(hv_, hv_, 0, 1); \
                v2f h23_ = __builtin_shufflevector(hv_, hv_, 2, 3); \
                pkfma_ll(a0, h01_, Wa); pkfma_hh(a1, h01_, Wb); \
                pkfma_ll(a2, h23_, Wc); pkfma_hh(a3, h23_, Wd_); \
            }
            MAC4(0,  WP0,  WP1,  WP2,  WP3)
            MAC4(1,  WP4,  WP5,  WP6,  WP7)
            MAC4(2,  WP8,  WP9,  WP10, WP11)
            MAC4(3,  WP12, WP13, WP14, WP15)
            MAC4(4,  WP16, WP17, WP18, WP19)
            MAC4(5,  WP20, WP21, WP22, WP23)
            MAC4(6,  WP24, WP25, WP26, WP27)
            MAC4(7,  WP28, WP29, WP30, WP31)
            MAC4(8,  WP32, WP33, WP34, WP35)
            MAC4(9,  WP36, WP37, WP38, WP39)
            MAC4(10, WP40, WP41, WP42, WP43)
            MAC4(11, WP44, WP45, WP46, WP47)
            MAC4(12, WP48, WP49, WP50, WP51)
            MAC4(13, WP52, WP53, WP54, WP55)
            MAC4(14, WP56, WP57, WP58, WP59)
            MAC4(15, WP60, WP61, WP62, WP63)
            #undef MAC4

            const v2f zown = (a0 + a1) + (a2 + a3);  // own (zA, zB) pair
            zbme[u] = zown;                          // ds_write_b64
            __syncthreads();                         // B(t+1): pairs exchanged

            const v2f zoth = zbot[u];                // only the OTHER pair
            const v2f zij = (wid == 0) ? zown : zoth;
            const v2f zfo = (wid == 0) ? zoth : zown;

            // redundant unit update -- bit-identical in both producer waves
            c0 = fsigmoid(zfo.x + 1.0f) * c0 + fsigmoid(zij.x) * ftanh(zij.y);
            const float h = fsigmoid(zfo.y) * ftanh(c0);

            myring[t & 1][u] = h;  // plain h ring, b32 write
        }
        __syncthreads();  // B(TT+1)
    } else {
        // ================= CONSUMER: layer 1 + dense + store =================
        const float w1v0 = W1[u * 4 + 0], w1v1 = W1[u * 4 + 1];
        const float w1v2 = W1[u * 4 + 2], w1v3 = W1[u * 4 + 3];
        const float w1h0 = W1[256], w1h1 = W1[257], w1h2 = W1[258], w1h3 = W1[259];
        const float b10 = b1[0], b11 = b1[1], b12 = b1[2], b13 = b1[3];
        const float wd = Wd[0], bdv = bd[0];

        float c1 = 0.f, h1 = 0.f, oval = 0.f;

        // reads wave0's ring one step lagged: slot s&1 written in
        // (B(s+1),B(s+2))... wait-free as in r4: written in (B(s),B(s+1))
        // post-barrier phase of iter s, read after B(s+1), rewritten in the
        // post-barrier phase of iter s+2 (after B(s+2)) -> race-free.
        #define L1STEP(s) { \
            const float hu = ringS0[(s) & 1][u];  /* 4B stride: conflict-free */ \
            float p0 = hu * w1v0, p1 = hu * w1v1, p2 = hu * w1v2, p3 = hu * w1v3; \
            _Pragma("unroll") \
            for (int m = 1; m < 64; m <<= 1) { \
                p0 += __shfl_xor(p0, m, 64); \
                p1 += __shfl_xor(p1, m, 64); \
                p2 += __shfl_xor(p2, m, 64); \
                p3 += __shfl_xor(p3, m, 64); \
            } \
            const float z1i = p0 + fmaf(h1, w1h0, b10); \
            const float z1j = p1 + fmaf(h1, w1h1, b11); \
            const float z1f = p2 + fmaf(h1, w1h2, b12); \
            const float z1o = p3 + fmaf(h1, w1h3, b13); \
            c1 = fsigmoid(z1f + 1.0f) * c1 + fsigmoid(z1i) * ftanh(z1j); \
            h1 = fsigmoid(z1o) * ftanh(c1); \
            const float ov = fmaf(h1, wd, bdv); \
            if (((s) & 63) == u) oval = ov; \
            if (((s) & 63) == 63) outrow[((s) & ~63) + u] = oval; \
        }

        for (int t = 0; t < TT; ++t) {
            __syncthreads();  // B(t+1)
            if (t > 0) L1STEP(t - 1)
        }
        __syncthreads();  // B(TT+1) -- makes ring slot (TT-1)&1 visible
        L1STEP(TT - 1)
        #undef L1STEP
    }
}

extern "C" void kernel_launch(void* const* d_in, const int* in_sizes, int n_in,
                              void* d_out, int out_size, void* d_ws, size_t ws_size,
                              hipStream_t stream) {
    const float* x  = (const float*)d_in[0];
    const float* W0 = (const float*)d_in[1];
    const float* b0 = (const float*)d_in[2];
    const float* W1 = (const float*)d_in[3];
    const float* b1 = (const float*)d_in[4];
    const float* Wd = (const float*)d_in[5];
    const float* bd = (const float*)d_in[6];
    float* out = (float*)d_out;
    lstm_ts_kernel<<<BB, NTHR, 0, stream>>>(x, W0, b0, W1, b1, Wd, bd, out);
}